// Round 1
// baseline (3084.519 us; speedup 1.0000x reference)
//
#include <hip/hip_runtime.h>

#define TDIM 2048
#define FDIM 128

// LDS layout (floats):
//  X:  [2][24][24]        @ 0      size 1152
//  Y1: [32][22][24(pad)]  @ 1152   size 16896
//  Y2: [32][20][20]       @ 18048  size 12800
//  Y3: [32][18][20(pad)]  @ 0      size 11520  (overlaps X+Y1, both dead by then)
//  W:  [CI*9][32]         @ 30848  size 9216 max (re-staged per conv)
// total 40064 floats = 160256 B (+ small row arrays) <= 160 KiB LDS
__device__ __forceinline__ float4 ld4(const float* p) {
    return *reinterpret_cast<const float4*>(p);
}

template<int CI, int HO, int WO, int IN_RS, int IN_CS, int OUT_RS, int OUT_CS, bool RELU>
__device__ void conv32(const float* __restrict__ inb, float* __restrict__ outb,
                       const float* __restrict__ wb, float bias,
                       int c, int s, int t_base, int f_base)
{
    constexpr int RD = ((WO + 2 + 3) / 4) * 4;  // row floats to read (float4 multiple)
    for (int i = s; i < HO; i += 8) {
        float acc[WO];
#pragma unroll
        for (int j = 0; j < WO; ++j) acc[j] = bias;
#pragma unroll 2
        for (int ci = 0; ci < CI; ++ci) {
#pragma unroll
            for (int u = 0; u < 3; ++u) {
                const float* row = inb + ci * IN_CS + (i + u) * IN_RS;
                float r[RD];
#pragma unroll
                for (int q = 0; q < RD / 4; ++q) {
                    float4 v4 = ld4(row + q * 4);
                    r[q * 4 + 0] = v4.x; r[q * 4 + 1] = v4.y;
                    r[q * 4 + 2] = v4.z; r[q * 4 + 3] = v4.w;
                }
#pragma unroll
                for (int v = 0; v < 3; ++v) {
                    float wv = wb[(ci * 9 + u * 3 + v) * 32 + c];
#pragma unroll
                    for (int j = 0; j < WO; ++j)
                        acc[j] = fmaf(r[j + v], wv, acc[j]);
                }
            }
        }
        // write with SAME-padding validity + relu
        int t = t_base + i;
        bool trow = (t >= 0) && (t < TDIM);
#pragma unroll
        for (int j = 0; j < WO; ++j) {
            int f = f_base + j;
            float val = RELU ? fmaxf(acc[j], 0.0f) : acc[j];
            if (!trow || f < 0 || f >= FDIM) val = 0.0f;
            outb[c * OUT_CS + i * OUT_RS + j] = val;
        }
    }
}

__global__ __launch_bounds__(256, 1)
void fused_reconst_kernel(const float* __restrict__ pr, const float* __restrict__ onset,
                          const int* __restrict__ tf,
                          const float* __restrict__ W1, const float* __restrict__ B1,
                          const float* __restrict__ W2, const float* __restrict__ B2,
                          const float* __restrict__ W3, const float* __restrict__ B3,
                          const float* __restrict__ W4, const float* __restrict__ B4,
                          float* __restrict__ out)
{
    __shared__ float lds[40064];
    __shared__ int   rowIdx[24];
    __shared__ float rowOnset[24];

    const int tid = threadIdx.x;
    const int f0 = blockIdx.x * 16;
    const int t0 = blockIdx.y * 16;
    const int b  = blockIdx.z;

    float* X  = lds;           // [2][24][24]
    float* Y1 = lds + 1152;    // [32][22][24]
    float* Y2 = lds + 18048;   // [32][20][20]
    float* Y3 = lds;           // [32][18][20]
    float* WS = lds + 30848;   // weights (transposed)

    // per-row tatum index: idx = upper_bound(tf[1:257], t), clipped to 255
    if (tid < 24) {
        int t = t0 - 4 + tid;
        int idx = 0; float ons = 0.0f;
        if (t >= 0 && t < TDIM) {
            const int* a = tf + b * 257 + 1;
            int lo = 0, hi = 256;
            while (lo < hi) { int mid = (lo + hi) >> 1; if (a[mid] <= t) lo = mid + 1; else hi = mid; }
            idx = lo < 255 ? lo : 255;
            ons = onset[b * 256 + idx];
        }
        rowIdx[tid] = idx; rowOnset[tid] = ons;
    }
    // stage W1 -> WS[k][co], k = ci*9 + 3u + v  (CI=2 -> 18x32)
    for (int e = tid; e < 18 * 32; e += 256) {
        int k = e >> 5, co = e & 31;
        WS[e] = W1[co * 18 + k];
    }
    __syncthreads();

    // stage input tile X[2][24][24] via tatum gather
    for (int e = tid; e < 576; e += 256) {
        int i = e / 24, j = e % 24;
        int t = t0 - 4 + i, f = f0 - 4 + j;
        bool valid = (t >= 0) && (t < TDIM) && (f >= 0) && (f < FDIM);
        float v0 = 0.0f, v1 = 0.0f;
        if (valid) {
            v0 = pr[(b * 256 + rowIdx[i]) * 128 + f];
            v1 = rowOnset[i];
        }
        X[e]       = v0;   // channel 0: pitch
        X[576 + e] = v1;   // channel 1: onset
    }
    __syncthreads();

    const int c = tid & 31, s = tid >> 5;

    // conv1: X[2][24][24] -> Y1[32][22][24pad], relu
    conv32<2, 22, 22, 24, 576, 24, 528, true>(X, Y1, WS, B1[c], c, s, t0 - 3, f0 - 3);
    __syncthreads();

    // stage W2 (288x32)
    for (int e = tid; e < 288 * 32; e += 256) {
        int k = e >> 5, co = e & 31;
        WS[e] = W2[co * 288 + k];
    }
    __syncthreads();

    // conv2: Y1 -> Y2[32][20][20], relu
    conv32<32, 20, 20, 24, 528, 20, 400, true>(Y1, Y2, WS, B2[c], c, s, t0 - 2, f0 - 2);
    __syncthreads();

    // stage W3
    for (int e = tid; e < 288 * 32; e += 256) {
        int k = e >> 5, co = e & 31;
        WS[e] = W3[co * 288 + k];
    }
    __syncthreads();

    // conv3: Y2 -> Y3[32][18][20pad], relu (Y3 overlaps dead X/Y1)
    conv32<32, 18, 18, 20, 400, 20, 360, true>(Y2, Y3, WS, B3[c], c, s, t0 - 1, f0 - 1);
    __syncthreads();

    // stage W4 (linear 288)
    for (int e = tid; e < 288; e += 256) WS[e] = W4[e];
    __syncthreads();

    // conv4: Y3[32][18][20] -> out[16][16], no relu; one thread per pixel
    {
        int i = tid >> 4, j = tid & 15;
        float acc = B4[0];
        for (int ci = 0; ci < 32; ++ci) {
#pragma unroll
            for (int u = 0; u < 3; ++u) {
#pragma unroll
                for (int v = 0; v < 3; ++v) {
                    acc = fmaf(Y3[ci * 360 + (i + u) * 20 + (j + v)],
                               WS[ci * 9 + u * 3 + v], acc);
                }
            }
        }
        out[((long)b * TDIM + (t0 + i)) * FDIM + (f0 + j)] = acc;
    }
}

extern "C" void kernel_launch(void* const* d_in, const int* in_sizes, int n_in,
                              void* d_out, int out_size, void* d_ws, size_t ws_size,
                              hipStream_t stream) {
    const float* pr    = (const float*)d_in[0];
    const float* onset = (const float*)d_in[1];
    const int*   tf    = (const int*)d_in[2];
    const float* W1 = (const float*)d_in[3];
    const float* B1 = (const float*)d_in[4];
    const float* W2 = (const float*)d_in[5];
    const float* B2 = (const float*)d_in[6];
    const float* W3 = (const float*)d_in[7];
    const float* B3 = (const float*)d_in[8];
    const float* W4 = (const float*)d_in[9];
    const float* B4 = (const float*)d_in[10];
    float* out = (float*)d_out;

    dim3 grid(FDIM / 16, TDIM / 16, 8);
    fused_reconst_kernel<<<grid, 256, 0, stream>>>(pr, onset, tf,
                                                   W1, B1, W2, B2, W3, B3, W4, B4, out);
}

// Round 2
// 338.881 us; speedup vs baseline: 9.1021x; 9.1021x over previous
//
#include <hip/hip_runtime.h>
#include <hip/hip_bf16.h>

#define TDIM 2048
#define FDIM 128

typedef __attribute__((ext_vector_type(8))) short short8;
typedef __attribute__((ext_vector_type(4))) float f32x4;
typedef __attribute__((ext_vector_type(8))) unsigned short ushort8;

__device__ __forceinline__ unsigned short f2bf(float v) {
    __bf16 h = (__bf16)v;
    return __builtin_bit_cast(unsigned short, h);
}

// ---------------- weight prep: transpose to [uv][co][ci] bf16 in d_ws ----------------
// layout (elements): Wt1 @0     [12][32][8]   (uv 9..11 and ci 2..7 zero)   3072
//                    Wt2 @3072  [9][32][32]                                  9216
//                    Wt3 @12288 [9][32][32]                                  9216
//                    Wt4 @21504 [9][16][32]   (co 1..15 zero)                4608
__global__ void prep_weights_kernel(const float* __restrict__ W1, const float* __restrict__ W2,
                                    const float* __restrict__ W3, const float* __restrict__ W4,
                                    unsigned short* __restrict__ wt)
{
    for (int e = blockIdx.x * 256 + threadIdx.x; e < 26112; e += gridDim.x * 256) {
        float v = 0.0f;
        if (e < 3072) {
            int uv = e >> 8, co = (e >> 3) & 31, ci = e & 7;
            if (uv < 9 && ci < 2) v = W1[co * 18 + ci * 9 + uv];
        } else if (e < 12288) {
            int q = e - 3072; int uv = q >> 10, co = (q >> 5) & 31, ci = q & 31;
            v = W2[co * 288 + ci * 9 + uv];
        } else if (e < 21504) {
            int q = e - 12288; int uv = q >> 10, co = (q >> 5) & 31, ci = q & 31;
            v = W3[co * 288 + ci * 9 + uv];
        } else {
            int q = e - 21504; int uv = q >> 9, co = (q >> 5) & 15, ci = q & 31;
            if (co == 0) v = W4[ci * 9 + uv];
        }
        wt[e] = f2bf(v);
    }
}

// pack 4 fp32 accumulators -> 4 bf16 (8B), relu + validity mask
__device__ __forceinline__ uint2 pack4(f32x4 c, bool valid) {
    unsigned short h[4];
#pragma unroll
    for (int k = 0; k < 4; ++k) {
        float v = fmaxf(c[k], 0.0f);
        h[k] = valid ? f2bf(v) : (unsigned short)0;
    }
    uint2 r;
    r.x = (unsigned)h[0] | ((unsigned)h[1] << 16);
    r.y = (unsigned)h[2] | ((unsigned)h[3] << 16);
    return r;
}

// conv2/conv3: in [WI][WI][32] bf16 -> out [WO][WO][32] bf16, weights [9][32][32] in LDS
template<int WI, int WO>
__device__ __forceinline__ void conv_mid(const char* __restrict__ inb, char* __restrict__ outb,
                                         const char* __restrict__ wlds, const float* __restrict__ bias,
                                         int wave, int lane, int t_base, int f_base)
{
    const int lm = lane & 15, g = lane >> 4;
    short8 wa0[9], wa1[9];
#pragma unroll
    for (int uv = 0; uv < 9; ++uv) {
        wa0[uv] = *(const short8*)(wlds + uv * 2048 + lm * 64 + g * 16);
        wa1[uv] = *(const short8*)(wlds + uv * 2048 + (16 + lm) * 64 + g * 16);
    }
    f32x4 bias0, bias1;
#pragma unroll
    for (int r = 0; r < 4; ++r) { bias0[r] = bias[g * 4 + r]; bias1[r] = bias[16 + g * 4 + r]; }

    constexpr int NPX = WO * WO;
    constexpr int NG = (NPX + 15) / 16;
    for (int grp = wave; grp < NG; grp += 4) {
        int m = grp * 16 + lm;
        bool mv = m < NPX;
        int mc = mv ? m : NPX - 1;
        int i = mc / WO, j = mc - i * WO;
        const char* base = inb + (i * WI + j) * 64 + g * 16;
        f32x4 c0 = bias0, c1 = bias1;
#pragma unroll
        for (int u = 0; u < 3; ++u)
#pragma unroll
            for (int v = 0; v < 3; ++v) {
                short8 bf = *(const short8*)(base + (u * WI + v) * 64);
                c0 = __builtin_amdgcn_mfma_f32_16x16x32_bf16(wa0[u * 3 + v], bf, c0, 0, 0, 0);
                c1 = __builtin_amdgcn_mfma_f32_16x16x32_bf16(wa1[u * 3 + v], bf, c1, 0, 0, 0);
            }
        if (mv) {
            int t = t_base + i, f = f_base + j;
            bool valid = (t >= 0) && (t < TDIM) && (f >= 0) && (f < FDIM);
            *(uint2*)(outb + m * 64 + g * 8)      = pack4(c0, valid);
            *(uint2*)(outb + m * 64 + 32 + g * 8) = pack4(c1, valid);
        }
    }
}

// conv1: X [24][24][8] bf16 (ch0=pr, ch1=onset, rest 0), W1lds [12][32][8], out Y1 [22][22][32]
// K-order: k = uv*8 + ci, K=96 (3 mfma), uv>=9 slots are zero weights
__device__ __forceinline__ void conv1_compute(const char* __restrict__ X, const char* __restrict__ w1,
                                              char* __restrict__ Y1, const float* __restrict__ bias,
                                              int wave, int lane, int t_base, int f_base)
{
    const int lm = lane & 15, g = lane >> 4;
    short8 wa0[3], wa1[3];
    int duv[3];
#pragma unroll
    for (int jj = 0; jj < 3; ++jj) {
        int uv = 4 * jj + g;                 // uv for this lane's k-block
        wa0[jj] = *(const short8*)(w1 + uv * 512 + lm * 16);          // zero for uv>=9
        wa1[jj] = *(const short8*)(w1 + uv * 512 + (16 + lm) * 16);
        int uvc = uv <= 8 ? uv : 0;          // clamp for safe addr; weights are 0 there anyway
        int u = uvc / 3, v = uvc - u * 3;
        duv[jj] = (u * 24 + v) * 16;
    }
    f32x4 bias0, bias1;
#pragma unroll
    for (int r = 0; r < 4; ++r) { bias0[r] = bias[g * 4 + r]; bias1[r] = bias[16 + g * 4 + r]; }

    constexpr int NPX = 22 * 22;
    constexpr int NG = (NPX + 15) / 16;      // 31
    for (int grp = wave; grp < NG; grp += 4) {
        int m = grp * 16 + lm;
        bool mv = m < NPX;
        int mc = mv ? m : NPX - 1;
        int i = mc / 22, j = mc - i * 22;
        const char* base = X + (i * 24 + j) * 16;
        f32x4 c0 = bias0, c1 = bias1;
#pragma unroll
        for (int jj = 0; jj < 3; ++jj) {
            short8 bf = *(const short8*)(base + duv[jj]);
            c0 = __builtin_amdgcn_mfma_f32_16x16x32_bf16(wa0[jj], bf, c0, 0, 0, 0);
            c1 = __builtin_amdgcn_mfma_f32_16x16x32_bf16(wa1[jj], bf, c1, 0, 0, 0);
        }
        if (mv) {
            int t = t_base + i, f = f_base + j;
            bool valid = (t >= 0) && (t < TDIM) && (f >= 0) && (f < FDIM);
            *(uint2*)(Y1 + m * 64 + g * 8)      = pack4(c0, valid);
            *(uint2*)(Y1 + m * 64 + 32 + g * 8) = pack4(c1, valid);
        }
    }
}

// conv4: Y3 [18][18][32] -> out 16x16 fp32 global, weights [9][16][32] (co 1..15 zero)
__device__ __forceinline__ void conv4_compute(const char* __restrict__ Y3, const char* __restrict__ w4,
                                              const float* __restrict__ b4, float* __restrict__ out,
                                              int wave, int lane, int b, int t0, int f0)
{
    const int lm = lane & 15, g = lane >> 4;
    short8 wa[9];
#pragma unroll
    for (int uv = 0; uv < 9; ++uv)
        wa[uv] = *(const short8*)(w4 + uv * 1024 + lm * 64 + g * 16);
    float bv = b4[0];
    for (int grp = wave; grp < 16; grp += 4) {
        f32x4 c = {0.0f, 0.0f, 0.0f, 0.0f};
#pragma unroll
        for (int u = 0; u < 3; ++u)
#pragma unroll
            for (int v = 0; v < 3; ++v) {
                short8 bf = *(const short8*)(Y3 + ((grp + u) * 18 + lm + v) * 64 + g * 16);
                c = __builtin_amdgcn_mfma_f32_16x16x32_bf16(wa[u * 3 + v], bf, c, 0, 0, 0);
            }
        if (g == 0)
            out[((long)b * TDIM + (t0 + grp)) * FDIM + f0 + lm] = c[0] + bv;
    }
}

// LDS overlay (bytes):
//  [0..9216)      X  [24][24][8]     (dead after conv1)
//  [9216..15360)  W1 [12][32][8]     (dead after conv1)
//  [0..25600)     Y2 [20][20][32]    (written by conv2 over dead X/W1)
//  [25600..56576) Y1 [22][22][32]    (dead after conv2)
//  [25600..46336) Y3 [18][18][32]    (written by conv3 over dead Y1)
//  [56576..75008) WB [9][32][32]     (W2 upfront; restaged W3, W4)
__global__ __launch_bounds__(256, 2)
void fused_mfma_kernel(const float* __restrict__ pr, const float* __restrict__ onset,
                       const int* __restrict__ tf,
                       const float* __restrict__ b1, const float* __restrict__ b2,
                       const float* __restrict__ b3, const float* __restrict__ b4,
                       const unsigned short* __restrict__ wt, float* __restrict__ out)
{
    __shared__ __attribute__((aligned(16))) char lds[75008];
    __shared__ int   rowIdx[24];
    __shared__ float rowOnset[24];

    const int tid = threadIdx.x;
    const int lane = tid & 63, wave = tid >> 6;
    const int f0 = blockIdx.x * 16;
    const int t0 = blockIdx.y * 16;
    const int b  = blockIdx.z;

    char* X  = lds;
    char* W1 = lds + 9216;
    char* Y2 = lds;
    char* Y1 = lds + 25600;
    char* Y3 = lds + 25600;
    char* WB = lds + 56576;
    const char* wtb = (const char*)wt;

    // per-row tatum index for the 24-row halo
    if (tid < 24) {
        int t = t0 - 4 + tid;
        int idx = 0; float ons = 0.0f;
        if (t >= 0 && t < TDIM) {
            const int* a = tf + b * 257 + 1;
            int lo = 0, hi = 256;
            while (lo < hi) { int mid = (lo + hi) >> 1; if (a[mid] <= t) lo = mid + 1; else hi = mid; }
            idx = lo < 255 ? lo : 255;
            if (t < tf[b * 257 + 256]) ons = onset[b * 256 + idx]; else idx = idx; // padding rows stay 0 via valid check below
        }
        rowIdx[tid] = idx; rowOnset[tid] = ons;
    }
    // stage W1 (384x16B) and W2 (1152x16B) from prepped ws
    for (int ch = tid; ch < 384; ch += 256)
        *(short8*)(W1 + ch * 16) = *(const short8*)(wtb + ch * 16);
    for (int ch = tid; ch < 1152; ch += 256)
        *(short8*)(WB + ch * 16) = *(const short8*)(wtb + 6144 + ch * 16);
    __syncthreads();

    // stage X [24][24][8] via tatum gather (bf16, channels-last)
    for (int p = tid; p < 576; p += 256) {
        int i = p / 24, j = p - (p / 24) * 24;
        int t = t0 - 4 + i, f = f0 - 4 + j;
        float v0 = 0.0f, v1 = 0.0f;
        if (t >= 0 && t < TDIM && f >= 0 && f < FDIM && t < tf[b * 257 + 256]) {
            v0 = pr[(b * 256 + rowIdx[i]) * 128 + f];
            v1 = rowOnset[i];
        }
        ushort8 xv = {f2bf(v0), f2bf(v1), 0, 0, 0, 0, 0, 0};
        *(ushort8*)(X + p * 16) = xv;
    }
    __syncthreads();

    conv1_compute(X, W1, Y1, b1, wave, lane, t0 - 3, f0 - 3);
    __syncthreads();

    conv_mid<22, 20>(Y1, Y2, WB, b2, wave, lane, t0 - 2, f0 - 2);
    __syncthreads();

    for (int ch = tid; ch < 1152; ch += 256)      // stage W3
        *(short8*)(WB + ch * 16) = *(const short8*)(wtb + 24576 + ch * 16);
    __syncthreads();

    conv_mid<20, 18>(Y2, Y3, WB, b3, wave, lane, t0 - 1, f0 - 1);
    __syncthreads();

    for (int ch = tid; ch < 576; ch += 256)       // stage W4
        *(short8*)(WB + ch * 16) = *(const short8*)(wtb + 43008 + ch * 16);
    __syncthreads();

    conv4_compute(Y3, WB, b4, out, wave, lane, b, t0, f0);
}

extern "C" void kernel_launch(void* const* d_in, const int* in_sizes, int n_in,
                              void* d_out, int out_size, void* d_ws, size_t ws_size,
                              hipStream_t stream) {
    const float* pr    = (const float*)d_in[0];
    const float* onset = (const float*)d_in[1];
    const int*   tf    = (const int*)d_in[2];
    const float* W1 = (const float*)d_in[3];
    const float* B1 = (const float*)d_in[4];
    const float* W2 = (const float*)d_in[5];
    const float* B2 = (const float*)d_in[6];
    const float* W3 = (const float*)d_in[7];
    const float* B3 = (const float*)d_in[8];
    const float* W4 = (const float*)d_in[9];
    const float* B4 = (const float*)d_in[10];
    float* out = (float*)d_out;
    unsigned short* wt = (unsigned short*)d_ws;

    prep_weights_kernel<<<32, 256, 0, stream>>>(W1, W2, W3, W4, wt);
    dim3 grid(FDIM / 16, TDIM / 16, 8);
    fused_mfma_kernel<<<grid, 256, 0, stream>>>(pr, onset, tf, B1, B2, B3, B4, wt, out);
}

// Round 3
// 250.536 us; speedup vs baseline: 12.3117x; 1.3526x over previous
//
#include <hip/hip_runtime.h>
#include <hip/hip_bf16.h>

#define TDIM 2048
#define FDIM 128

typedef __attribute__((ext_vector_type(8))) short short8;
typedef __attribute__((ext_vector_type(4))) float f32x4;
typedef __attribute__((ext_vector_type(8))) unsigned short ushort8;

__device__ __forceinline__ unsigned short f2bf(float v) {
    __bf16 h = (__bf16)v;
    return __builtin_bit_cast(unsigned short, h);
}

// ---------------- weight prep -> bf16, k-plane-major, in d_ws ----------------
// elements (bf16):
//  wt1 @ 0     : [12 uv][32 co][8 ci]                  3072   (uv>=9, ci>=2 zero)
//  wt2 @ 3072  : [4 g][9 uv][32 co][8 ci]  ci=g*8+ci8  9216
//  wt3 @ 12288 : [4 g][9 uv][32 co][8 ci]              9216
//  wt4 @ 21504 : [4 g][9 uv][16 co][8 ci]              4608   (co>0 zero)
__global__ void prep_weights_kernel(const float* __restrict__ W1, const float* __restrict__ W2,
                                    const float* __restrict__ W3, const float* __restrict__ W4,
                                    unsigned short* __restrict__ wt)
{
    for (int e = blockIdx.x * 256 + threadIdx.x; e < 26112; e += gridDim.x * 256) {
        float v = 0.0f;
        if (e < 3072) {
            int uv = e >> 8, co = (e >> 3) & 31, ci = e & 7;
            if (uv < 9 && ci < 2) v = W1[co * 18 + ci * 9 + uv];
        } else if (e < 12288) {
            int q = e - 3072;
            int g = q / 2304, r = q % 2304;
            int uv = r >> 8, co = (r >> 3) & 31, ci = g * 8 + (r & 7);
            v = W2[co * 288 + ci * 9 + uv];
        } else if (e < 21504) {
            int q = e - 12288;
            int g = q / 2304, r = q % 2304;
            int uv = r >> 8, co = (r >> 3) & 31, ci = g * 8 + (r & 7);
            v = W3[co * 288 + ci * 9 + uv];
        } else {
            int q = e - 21504;
            int g = q / 1152, r = q % 1152;
            int uv = r >> 7, co = (r >> 3) & 15, ci = g * 8 + (r & 7);
            if (co == 0) v = W4[ci * 9 + uv];
        }
        wt[e] = f2bf(v);
    }
}

// pack 4 fp32 -> 4 bf16 (8B), relu + validity mask
__device__ __forceinline__ uint2 pack4(f32x4 c, bool valid) {
    unsigned short h[4];
#pragma unroll
    for (int k = 0; k < 4; ++k) {
        float v = fmaxf(c[k], 0.0f);
        h[k] = valid ? f2bf(v) : (unsigned short)0;
    }
    uint2 r;
    r.x = (unsigned)h[0] | ((unsigned)h[1] << 16);
    r.y = (unsigned)h[2] | ((unsigned)h[3] << 16);
    return r;
}

#define NWAVES 8

// conv2/conv3: in planes [4][WI*WI][16B] -> out planes [4][WO*WO][16B]
// weights (LDS) planes [4 g][9 uv][32 co][16B]
template<int WI, int WO, int PSI, int PSO>
__device__ __forceinline__ void conv_mid(const char* __restrict__ inb, char* __restrict__ outb,
                                         const char* __restrict__ wlds, const float* __restrict__ bias,
                                         int wave, int lane, int t_base, int f_base)
{
    const int lm = lane & 15, g = lane >> 4;
    const char* wp = wlds + g * 4608;
    short8 wa0[9], wa1[9];
#pragma unroll
    for (int uv = 0; uv < 9; ++uv) {
        wa0[uv] = *(const short8*)(wp + (uv * 32 + lm) * 16);
        wa1[uv] = *(const short8*)(wp + (uv * 32 + 16 + lm) * 16);
    }
    f32x4 bias0 = *(const f32x4*)(bias + g * 4);
    f32x4 bias1 = *(const f32x4*)(bias + 16 + g * 4);

    const char* inp = inb + g * PSI;
    constexpr int NPX = WO * WO;
    constexpr int NG = (NPX + 15) / 16;
    for (int grp = wave; grp < NG; grp += NWAVES) {
        int m = grp * 16 + lm;
        bool mv = m < NPX;
        int mc = mv ? m : NPX - 1;
        int i = mc / WO, j = mc - i * WO;
        const char* base = inp + (i * WI + j) * 16;
        f32x4 c0 = bias0, c1 = bias1;
#pragma unroll
        for (int u = 0; u < 3; ++u)
#pragma unroll
            for (int v = 0; v < 3; ++v) {
                short8 bf = *(const short8*)(base + (u * WI + v) * 16);
                c0 = __builtin_amdgcn_mfma_f32_16x16x32_bf16(wa0[u * 3 + v], bf, c0, 0, 0, 0);
                c1 = __builtin_amdgcn_mfma_f32_16x16x32_bf16(wa1[u * 3 + v], bf, c1, 0, 0, 0);
            }
        if (mv) {
            int t = t_base + i, f = f_base + j;
            bool valid = (t >= 0) && (t < TDIM) && (f >= 0) && (f < FDIM);
            char* wb = outb + (g >> 1) * PSO + m * 16 + (g & 1) * 8;
            *(uint2*)wb             = pack4(c0, valid);
            *(uint2*)(wb + 2 * PSO) = pack4(c1, valid);
        }
    }
}

// conv1: X [24*24 px][16B] (ch0=pr, ch1=onset, rest 0), W1 [12 uv][32 co][16B],
// out Y1 planes [4][22*22][16B].  k = uv*8+ci, K=96 (3 mfma), uv>=9 zero-weighted.
__device__ __forceinline__ void conv1_compute(const char* __restrict__ X, const char* __restrict__ w1,
                                              char* __restrict__ Y1, const float* __restrict__ bias,
                                              int wave, int lane, int t_base, int f_base)
{
    const int lm = lane & 15, g = lane >> 4;
    short8 wa0[3], wa1[3];
    int duv[3];
#pragma unroll
    for (int jj = 0; jj < 3; ++jj) {
        int uv = 4 * jj + g;
        wa0[jj] = *(const short8*)(w1 + uv * 512 + lm * 16);
        wa1[jj] = *(const short8*)(w1 + uv * 512 + (16 + lm) * 16);
        int uvc = uv <= 8 ? uv : 0;   // weights are zero there; clamp addr only
        int u = uvc / 3, v = uvc - u * 3;
        duv[jj] = (u * 24 + v) * 16;
    }
    f32x4 bias0 = *(const f32x4*)(bias + g * 4);
    f32x4 bias1 = *(const f32x4*)(bias + 16 + g * 4);

    constexpr int NPX = 22 * 22;
    constexpr int NG = (NPX + 15) / 16;  // 31
    for (int grp = wave; grp < NG; grp += NWAVES) {
        int m = grp * 16 + lm;
        bool mv = m < NPX;
        int mc = mv ? m : NPX - 1;
        int i = mc / 22, j = mc - i * 22;
        const char* base = X + (i * 24 + j) * 16;
        f32x4 c0 = bias0, c1 = bias1;
#pragma unroll
        for (int jj = 0; jj < 3; ++jj) {
            short8 bf = *(const short8*)(base + duv[jj]);
            c0 = __builtin_amdgcn_mfma_f32_16x16x32_bf16(wa0[jj], bf, c0, 0, 0, 0);
            c1 = __builtin_amdgcn_mfma_f32_16x16x32_bf16(wa1[jj], bf, c1, 0, 0, 0);
        }
        if (mv) {
            int t = t_base + i, f = f_base + j;
            bool valid = (t >= 0) && (t < TDIM) && (f >= 0) && (f < FDIM);
            char* wb = Y1 + (g >> 1) * 7744 + m * 16 + (g & 1) * 8;
            *(uint2*)wb           = pack4(c0, valid);
            *(uint2*)(wb + 15488) = pack4(c1, valid);
        }
    }
}

// conv4: Y3 planes [4][18*18][16B] -> out 16x16 fp32; W4 planes [4 g][9 uv][16 co][16B]
__device__ __forceinline__ void conv4_compute(const char* __restrict__ Y3, const char* __restrict__ w4,
                                              const float* __restrict__ b4, float* __restrict__ out,
                                              int wave, int lane, int b, int t0, int f0)
{
    const int lm = lane & 15, g = lane >> 4;
    const char* wp = w4 + g * 2304;
    short8 wa[9];
#pragma unroll
    for (int uv = 0; uv < 9; ++uv)
        wa[uv] = *(const short8*)(wp + (uv * 16 + lm) * 16);
    float bv = b4[0];
    const char* yp = Y3 + g * 5184;
    for (int grp = wave; grp < 16; grp += NWAVES) {
        const char* base = yp + (grp * 18 + lm) * 16;
        f32x4 c = {0.0f, 0.0f, 0.0f, 0.0f};
#pragma unroll
        for (int u = 0; u < 3; ++u)
#pragma unroll
            for (int v = 0; v < 3; ++v) {
                short8 bf = *(const short8*)(base + (u * 18 + v) * 16);
                c = __builtin_amdgcn_mfma_f32_16x16x32_bf16(wa[u * 3 + v], bf, c, 0, 0, 0);
            }
        if (g == 0)
            out[((long)b * TDIM + (t0 + grp)) * FDIM + f0 + lm] = c[0] + bv;
    }
}

// LDS overlay (bytes):
//  [0..9216)      X  [576 px][16B]            (dead after conv1)
//  [9216..15360)  W1 [12][32][16B]            (dead after conv1)
//  [0..25600)     Y2 planes [4][400][16B]     (over dead X/W1)
//  [25600..56576) Y1 planes [4][484][16B]     (dead after conv2)
//  [25600..46336) Y3 planes [4][324][16B]     (over dead Y1)
//  [56576..75008) WB planes [4][9][32][16B]   (W2; restaged W3; then W4 [4][9][16][16B])
__global__ __launch_bounds__(512, 4)
void fused_mfma_kernel(const float* __restrict__ pr, const float* __restrict__ onset,
                       const int* __restrict__ tf,
                       const float* __restrict__ b1, const float* __restrict__ b2,
                       const float* __restrict__ b3, const float* __restrict__ b4,
                       const unsigned short* __restrict__ wt, float* __restrict__ out)
{
    __shared__ __attribute__((aligned(16))) char lds[75008];
    __shared__ int   rowIdx[24];
    __shared__ float rowOnset[24];

    const int tid = threadIdx.x;
    const int lane = tid & 63, wave = tid >> 6;
    const int f0 = blockIdx.x * 16;
    const int t0 = blockIdx.y * 16;
    const int b  = blockIdx.z;

    char* X  = lds;
    char* W1 = lds + 9216;
    char* Y2 = lds;
    char* Y1 = lds + 25600;
    char* Y3 = lds + 25600;
    char* WB = lds + 56576;
    const char* wtb = (const char*)wt;

    // per-row tatum index for the 24-row halo
    if (tid < 24) {
        int t = t0 - 4 + tid;
        int idx = 0; float ons = 0.0f;
        if (t >= 0 && t < TDIM) {
            const int* a = tf + b * 257 + 1;
            int lo = 0, hi = 256;
            while (lo < hi) { int mid = (lo + hi) >> 1; if (a[mid] <= t) lo = mid + 1; else hi = mid; }
            idx = lo < 255 ? lo : 255;
            ons = onset[b * 256 + idx];
        }
        rowIdx[tid] = idx; rowOnset[tid] = ons;
    }
    // stage W1 (384 chunks) and W2 (1152 chunks)
    for (int ch = tid; ch < 384; ch += 512)
        *(short8*)(W1 + ch * 16) = *(const short8*)(wtb + ch * 16);
    for (int ch = tid; ch < 1152; ch += 512)
        *(short8*)(WB + ch * 16) = *(const short8*)(wtb + 6144 + ch * 16);
    __syncthreads();

    // stage X [24][24] px, 16B each (bf16 ch0=pr, ch1=onset)
    for (int p = tid; p < 576; p += 512) {
        int i = p / 24, j = p - (p / 24) * 24;
        int t = t0 - 4 + i, f = f0 - 4 + j;
        float v0 = 0.0f, v1 = 0.0f;
        if (t >= 0 && t < TDIM && f >= 0 && f < FDIM) {
            v0 = pr[(b * 256 + rowIdx[i]) * 128 + f];
            v1 = rowOnset[i];
        }
        ushort8 xv = {f2bf(v0), f2bf(v1), 0, 0, 0, 0, 0, 0};
        *(ushort8*)(X + p * 16) = xv;
    }
    __syncthreads();

    conv1_compute(X, W1, Y1, b1, wave, lane, t0 - 3, f0 - 3);
    __syncthreads();

    conv_mid<22, 20, 7744, 6400>(Y1, Y2, WB, b2, wave, lane, t0 - 2, f0 - 2);
    __syncthreads();

    for (int ch = tid; ch < 1152; ch += 512)      // stage W3
        *(short8*)(WB + ch * 16) = *(const short8*)(wtb + 24576 + ch * 16);
    __syncthreads();

    conv_mid<20, 18, 6400, 5184>(Y2, Y3, WB, b3, wave, lane, t0 - 1, f0 - 1);
    __syncthreads();

    for (int ch = tid; ch < 576; ch += 512)       // stage W4
        *(short8*)(WB + ch * 16) = *(const short8*)(wtb + 43008 + ch * 16);
    __syncthreads();

    conv4_compute(Y3, WB, b4, out, wave, lane, b, t0, f0);
}

extern "C" void kernel_launch(void* const* d_in, const int* in_sizes, int n_in,
                              void* d_out, int out_size, void* d_ws, size_t ws_size,
                              hipStream_t stream) {
    const float* pr    = (const float*)d_in[0];
    const float* onset = (const float*)d_in[1];
    const int*   tf    = (const int*)d_in[2];
    const float* W1 = (const float*)d_in[3];
    const float* B1 = (const float*)d_in[4];
    const float* W2 = (const float*)d_in[5];
    const float* B2 = (const float*)d_in[6];
    const float* W3 = (const float*)d_in[7];
    const float* B3 = (const float*)d_in[8];
    const float* W4 = (const float*)d_in[9];
    const float* B4 = (const float*)d_in[10];
    float* out = (float*)d_out;
    unsigned short* wt = (unsigned short*)d_ws;

    prep_weights_kernel<<<32, 256, 0, stream>>>(W1, W2, W3, W4, wt);
    dim3 grid(FDIM / 16, TDIM / 16, 8);
    fused_mfma_kernel<<<grid, 512, 0, stream>>>(pr, onset, tf, B1, B2, B3, B4, wt, out);
}